// Round 3
// baseline (2332.486 us; speedup 1.0000x reference)
//
#include <hip/hip_runtime.h>
#include <math.h>

#define KCODES 4096
#define DIM    256
#define HW     4096
#define NPIX   65536
#define NQ     16777216   // 16*256*64*64
#define MP     32         // pixels per block
#define KC     128        // codes per LDS chunk
#define DC     32         // dims per LDS chunk
#define NBLK   (NPIX / MP)  // 2048

// ---------------------------------------------------------------------------
// numpy pairwise_sum bit-replication for a 256-element row of squares:
//   pairwise(a,256) = pairwise(a,128) + pairwise(a+128,128)
//   pairwise(b,128): r[j]=b[j]^2; for i=8..120 step 8: r[j]+=b[i+j]^2;
//                    ((r0+r1)+(r2+r3))+((r4+r5)+(r6+r7))
// Squares are rounded individually (contract off => no fma fusion).
// ---------------------------------------------------------------------------

// ee_k = np.sum(emb*emb, axis=1) in f32, one thread per code row (contiguous)
__global__ __launch_bounds__(256) void ee_np_kernel(const float* __restrict__ emb,
                                                    float* __restrict__ ee) {
#pragma clang fp contract(off)
    const int k = blockIdx.x * 256 + threadIdx.x;
    const float* a = emb + (size_t)k * DIM;
    float res[2];
    #pragma unroll
    for (int h = 0; h < 2; ++h) {
        const float* b = a + h * 128;
        float r[8];
        #pragma unroll
        for (int j = 0; j < 8; ++j) { const float x = b[j]; r[j] = x * x; }
        for (int i = 8; i < 128; i += 8) {
            #pragma unroll
            for (int j = 0; j < 8; ++j) { const float x = b[i + j]; r[j] += x * x; }
        }
        res[h] = ((r[0] + r[1]) + (r[2] + r[3])) + ((r[4] + r[5]) + (r[6] + r[7]));
    }
    ee[k] = res[0] + res[1];
}

// zz_n = np.sum(zf*zf, axis=1) in f32, one thread per pixel.
// Pixel n=(b,hw): element i lives at z[(b*DIM+i)*HW + hw] -> coalesced across
// consecutive threads (consecutive hw) at each i.
__global__ __launch_bounds__(256) void zz_np_kernel(const float* __restrict__ z,
                                                    float* __restrict__ zz) {
#pragma clang fp contract(off)
    const int n  = blockIdx.x * 256 + threadIdx.x;
    const int b  = n >> 12;
    const int hw = n & (HW - 1);
    const float* base = z + (size_t)b * DIM * HW + hw;
    float res[2];
    #pragma unroll
    for (int h = 0; h < 2; ++h) {
        const float* p = base + (size_t)(h * 128) * HW;
        float r[8];
        #pragma unroll
        for (int j = 0; j < 8; ++j) { const float x = p[(size_t)j * HW]; r[j] = x * x; }
        for (int i = 8; i < 128; i += 8) {
            #pragma unroll
            for (int j = 0; j < 8; ++j) { const float x = p[(size_t)(i + j) * HW]; r[j] += x * x; }
        }
        res[h] = ((r[0] + r[1]) + (r[2] + r[3])) + ((r[4] + r[5]) + (r[6] + r[7]));
    }
    zz[n] = res[0] + res[1];
}

// ---------------------------------------------------------------------------
// Fused distance + argmin + gather + loss.
// m_nk replicated as BLAS sgemm microkernel: single f32 accumulator,
// sequential fmaf over dims 0..255 ascending.
// d_nk = fl(fl(zz_n + ee_k) - 2*m_nk); argmin, first-index tie-break.
// ---------------------------------------------------------------------------
__global__ __launch_bounds__(256) void dist_kernel(const float* __restrict__ z,
                                                   const float* __restrict__ emb,
                                                   const float* __restrict__ ee,
                                                   const float* __restrict__ zz,
                                                   float* __restrict__ out,
                                                   float* __restrict__ part) {
    __shared__ float zs[MP][DIM + 4];     // [pixel][dim]
    __shared__ float est[DC][KC + 4];     // transposed emb chunk: [dim][code]
    __shared__ float ee_s[KC];
    __shared__ float zz_s[MP];
    __shared__ float red_v[MP][33];
    __shared__ int   red_i[MP][33];
    __shared__ int   idx_s[MP];
    __shared__ float wred[4];

    const int tid = threadIdx.x;
    const int tx  = tid & 31;
    const int ty  = tid >> 5;
    const int m0  = blockIdx.x * MP;       // first pixel (flat n = b*4096 + h*64 + w)
    const int bimg = m0 >> 12;
    const int hw0  = m0 & (HW - 1);

    // Stage z tile: zs[w'][c] = z[bimg][c][hw0 + w']
    for (int c = ty; c < DIM; c += 8)
        zs[tx][c] = z[((size_t)(bimg * DIM + c)) * HW + hw0 + tx];
    if (tid < MP) zz_s[tid] = zz[m0 + tid];

    float minv[4];
    int   mini[4];
    #pragma unroll
    for (int p = 0; p < 4; ++p) { minv[p] = 3.0e38f; mini[p] = 0; }

    const int rl = tid >> 3;   // 0..31: code row for staging
    const int cl = tid & 7;    // 0..7 : float4 over dims for staging

    for (int kc = 0; kc < KCODES / KC; ++kc) {
        float acc[4][4];
        #pragma unroll
        for (int p = 0; p < 4; ++p)
            #pragma unroll
            for (int q = 0; q < 4; ++q) acc[p][q] = 0.0f;

        for (int dc = 0; dc < DIM / DC; ++dc) {
            __syncthreads();   // protect est/ee_s from previous chunk's readers
            if (dc == 0 && tid < KC) ee_s[tid] = ee[kc * KC + tid];
            #pragma unroll
            for (int it = 0; it < 4; ++it) {
                const int kl = it * 32 + rl;
                const float4 v = *reinterpret_cast<const float4*>(
                    emb + (size_t)(kc * KC + kl) * DIM + dc * DC + cl * 4);
                est[cl * 4 + 0][kl] = v.x;
                est[cl * 4 + 1][kl] = v.y;
                est[cl * 4 + 2][kl] = v.z;
                est[cl * 4 + 3][kl] = v.w;
            }
            __syncthreads();
            #pragma unroll
            for (int g = 0; g < DC / 4; ++g) {
                float4 zr[4];
                #pragma unroll
                for (int p = 0; p < 4; ++p)
                    zr[p] = *reinterpret_cast<const float4*>(&zs[ty * 4 + p][dc * DC + g * 4]);
                float4 er[4];   // er[j] = codes 4tx..4tx+3 at dim g*4+j
                #pragma unroll
                for (int j = 0; j < 4; ++j)
                    er[j] = *reinterpret_cast<const float4*>(&est[g * 4 + j][tx * 4]);
                // sequential fmaf in ascending dim order (BLAS microkernel order)
                #pragma unroll
                for (int p = 0; p < 4; ++p) {
                    acc[p][0] = fmaf(zr[p].x, er[0].x, acc[p][0]);
                    acc[p][0] = fmaf(zr[p].y, er[1].x, acc[p][0]);
                    acc[p][0] = fmaf(zr[p].z, er[2].x, acc[p][0]);
                    acc[p][0] = fmaf(zr[p].w, er[3].x, acc[p][0]);
                    acc[p][1] = fmaf(zr[p].x, er[0].y, acc[p][1]);
                    acc[p][1] = fmaf(zr[p].y, er[1].y, acc[p][1]);
                    acc[p][1] = fmaf(zr[p].z, er[2].y, acc[p][1]);
                    acc[p][1] = fmaf(zr[p].w, er[3].y, acc[p][1]);
                    acc[p][2] = fmaf(zr[p].x, er[0].z, acc[p][2]);
                    acc[p][2] = fmaf(zr[p].y, er[1].z, acc[p][2]);
                    acc[p][2] = fmaf(zr[p].z, er[2].z, acc[p][2]);
                    acc[p][2] = fmaf(zr[p].w, er[3].z, acc[p][2]);
                    acc[p][3] = fmaf(zr[p].x, er[0].w, acc[p][3]);
                    acc[p][3] = fmaf(zr[p].y, er[1].w, acc[p][3]);
                    acc[p][3] = fmaf(zr[p].z, er[2].w, acc[p][3]);
                    acc[p][3] = fmaf(zr[p].w, er[3].w, acc[p][3]);
                }
            }
        }
        // d = fl(fl(zz+ee) - 2*m); ascending k within thread -> strict < keeps lowest idx
        #pragma unroll
        for (int q = 0; q < 4; ++q) {
            const int   kg = kc * KC + tx * 4 + q;
            const float en = ee_s[tx * 4 + q];
            #pragma unroll
            for (int p = 0; p < 4; ++p) {
                const float t = zz_s[ty * 4 + p] + en;   // fl(zz+ee)
                const float d = t - 2.0f * acc[p][q];    // 2*m exact; one final rounding
                if (d < minv[p]) { minv[p] = d; mini[p] = kg; }
            }
        }
    }

    // cross-lane argmin reduce (numpy tie-break: lowest index wins)
    #pragma unroll
    for (int p = 0; p < 4; ++p) {
        red_v[ty * 4 + p][tx] = minv[p];
        red_i[ty * 4 + p][tx] = mini[p];
    }
    __syncthreads();
    if (tid < MP) {
        float bv = red_v[tid][0];
        int   bi = red_i[tid][0];
        for (int t = 1; t < 32; ++t) {
            const float v  = red_v[tid][t];
            const int   i2 = red_i[tid][t];
            if (v < bv || (v == bv && i2 < bi)) { bv = v; bi = i2; }
        }
        idx_s[tid] = bi;
        out[NQ + m0 + tid] = (float)bi;
    }
    __syncthreads();

    // gather z_q (coalesced NCHW writes) + loss partial
    float lsum = 0.0f;
    const size_t ebase = (size_t)idx_s[tx] * DIM;
    for (int it = 0; it < DIM / 8; ++it) {
        const int c = it * 8 + ty;
        const float e = emb[ebase + c];
        out[((size_t)(bimg * DIM + c)) * HW + hw0 + tx] = e;
        const float diff = e - zs[tx][c];
        lsum += diff * diff;
    }
    #pragma unroll
    for (int off = 32; off >= 1; off >>= 1) lsum += __shfl_down(lsum, off, 64);
    if ((tid & 63) == 0) wred[tid >> 6] = lsum;
    __syncthreads();
    if (tid == 0) part[blockIdx.x] = wred[0] + wred[1] + wred[2] + wred[3];
}

// deterministic final loss reduction
__global__ __launch_bounds__(256) void loss_kernel(const float* __restrict__ part,
                                                   float* __restrict__ out) {
    __shared__ float wred[4];
    const int tid = threadIdx.x;
    float s = 0.0f;
    for (int i = tid; i < NBLK; i += 256) s += part[i];
    #pragma unroll
    for (int off = 32; off >= 1; off >>= 1) s += __shfl_down(s, off, 64);
    if ((tid & 63) == 0) wred[tid >> 6] = s;
    __syncthreads();
    if (tid == 0) {
        const float total = wred[0] + wred[1] + wred[2] + wred[3];
        out[NQ + NPIX] = 1.25f * total / 16777216.0f;  // (1+BETA) * mean
    }
}

extern "C" void kernel_launch(void* const* d_in, const int* in_sizes, int n_in,
                              void* d_out, int out_size, void* d_ws, size_t ws_size,
                              hipStream_t stream) {
    const float* z   = (const float*)d_in[0];
    const float* emb = (const float*)d_in[1];
    float* out  = (float*)d_out;
    float* ee   = (float*)d_ws;             // 4096 f32
    float* zz   = ee + KCODES;              // 65536 f32
    float* part = zz + NPIX;                // 2048 f32

    ee_np_kernel<<<KCODES / 256, 256, 0, stream>>>(emb, ee);
    zz_np_kernel<<<NPIX / 256, 256, 0, stream>>>(z, zz);
    dist_kernel<<<NBLK, 256, 0, stream>>>(z, emb, ee, zz, out, part);
    loss_kernel<<<1, 256, 0, stream>>>(part, out);
}

// Round 4
// 773.441 us; speedup vs baseline: 3.0157x; 3.0157x over previous
//
#include <hip/hip_runtime.h>
#include <math.h>

#define KCODES 4096
#define DIM    256
#define HW     4096
#define NPIX   65536
#define NQ     16777216   // 16*256*64*64
#define EPSW   1.0e-4f    // candidate window (>= 2*(ulp(256)+2*deltam))

typedef _Float16 f16x8 __attribute__((ext_vector_type(8)));
typedef float    f32x4 __attribute__((ext_vector_type(4)));

// XOR swizzle on tile-local byte offset: spreads 64B rows across banks
#define SWZ(x) ((x) ^ ((((x) >> 6) & 7) << 4))

// top4 insert, strict < (keeps lowest k on equal d given ascending-k feed)
#define INS4(V, I, dd, kk) do { \
  if ((dd) < V[3]) { \
    if ((dd) < V[1]) { \
      V[3]=V[2]; I[3]=I[2]; V[2]=V[1]; I[2]=I[1]; \
      if ((dd) < V[0]) { V[1]=V[0]; I[1]=I[0]; V[0]=(dd); I[0]=(kk); } \
      else             { V[1]=(dd); I[1]=(kk); } \
    } else { \
      if ((dd) < V[2]) { V[3]=V[2]; I[3]=I[2]; V[2]=(dd); I[2]=(kk); } \
      else             { V[3]=(dd); I[3]=(kk); } \
    } } } while(0)

// ---------------------------------------------------------------------------
// np-exact helpers (bit-replicate numpy f32 semantics — proven in R3)
// ---------------------------------------------------------------------------
__global__ __launch_bounds__(256) void ee_np_kernel(const float* __restrict__ emb,
                                                    float* __restrict__ ee) {
#pragma clang fp contract(off)
    const int k = blockIdx.x * 256 + threadIdx.x;
    const float* a = emb + (size_t)k * DIM;
    float res[2];
    #pragma unroll
    for (int h = 0; h < 2; ++h) {
        const float* b = a + h * 128;
        float r[8];
        #pragma unroll
        for (int j = 0; j < 8; ++j) { const float x = b[j]; r[j] = x * x; }
        for (int i = 8; i < 128; i += 8) {
            #pragma unroll
            for (int j = 0; j < 8; ++j) { const float x = b[i + j]; r[j] += x * x; }
        }
        res[h] = ((r[0] + r[1]) + (r[2] + r[3])) + ((r[4] + r[5]) + (r[6] + r[7]));
    }
    ee[k] = res[0] + res[1];
}

__global__ __launch_bounds__(256) void zz_np_kernel(const float* __restrict__ z,
                                                    float* __restrict__ zz) {
#pragma clang fp contract(off)
    const int n  = blockIdx.x * 256 + threadIdx.x;
    const int b  = n >> 12;
    const int hw = n & (HW - 1);
    const float* base = z + (size_t)b * DIM * HW + hw;
    float res[2];
    #pragma unroll
    for (int h = 0; h < 2; ++h) {
        const float* p = base + (size_t)(h * 128) * HW;
        float r[8];
        #pragma unroll
        for (int j = 0; j < 8; ++j) { const float x = p[(size_t)j * HW]; r[j] = x * x; }
        for (int i = 8; i < 128; i += 8) {
            #pragma unroll
            for (int j = 0; j < 8; ++j) { const float x = p[(size_t)(i + j) * HW]; r[j] += x * x; }
        }
        res[h] = ((r[0] + r[1]) + (r[2] + r[3])) + ((r[4] + r[5]) + (r[6] + r[7]));
    }
    zz[n] = res[0] + res[1];
}

__device__ float np_dist(const float* __restrict__ z, const float* __restrict__ emb,
                         const float* __restrict__ zz, const float* __restrict__ ee,
                         int n, int k) {
    const int b = n >> 12, hw = n & (HW - 1);
    const float* zp = z + (size_t)b * DIM * HW + hw;
    const float* ep = emb + (size_t)k * DIM;
    float m = 0.0f;
    for (int i = 0; i < DIM; ++i) m = fmaf(zp[(size_t)i * HW], ep[i], m);
    const float t = zz[n] + ee[k];
    return t - 2.0f * m;   // == fl(t - 2m) either way (product exact)
}

// ---------------------------------------------------------------------------
// FAST path kernels
// ---------------------------------------------------------------------------
__global__ __launch_bounds__(64) void init_kernel(int* cnt) {
    if (threadIdx.x == 0) *cnt = 0;
}

// emb -> tiled fp16 hi/lo, scaled by 4096 (exact pow2). Tile layout:
// addr(halfs) = (k>>7)*32768 + (d>>5)*4096 + (k&127)*32 + (d&31)
__global__ __launch_bounds__(256) void cvt_emb_kernel(const float* __restrict__ emb,
                                                      ushort* __restrict__ eh,
                                                      ushort* __restrict__ el) {
    const int t = threadIdx.x;
    const int k = blockIdx.x * 4 + (t >> 6);
    const int seg = t & 63;                       // 4-elem segment
    const float4 v = *reinterpret_cast<const float4*>(emb + (size_t)k * DIM + seg * 4);
    union H4 { _Float16 h[4]; short4 s; } uh, ul;
    const float vv[4] = {v.x, v.y, v.z, v.w};
    #pragma unroll
    for (int j = 0; j < 4; ++j) {
        const float es = vv[j] * 4096.0f;
        const _Float16 h = (_Float16)es;
        uh.h[j] = h;
        ul.h[j] = (_Float16)(es - (float)h);
    }
    const int s = seg >> 3, din = (seg & 7) * 4;
    const size_t addr = (size_t)(k >> 7) * 32768 + s * 4096 + (k & 127) * 32 + din;
    *reinterpret_cast<short4*>(eh + addr) = uh.s;
    *reinterpret_cast<short4*>(el + addr) = ul.s;
}

// z (NCHW) -> transposed tiled fp16 hi/lo [pixel][dim]:
// addr(halfs) = (px>>7)*32768 + (d>>5)*4096 + (px&127)*32 + (d&31)
__global__ __launch_bounds__(256) void cvt_z_kernel(const float* __restrict__ z,
                                                    ushort* __restrict__ zh,
                                                    ushort* __restrict__ zl) {
    __shared__ float ls[64][65];
    const int t = threadIdx.x;
    const int bid = blockIdx.x;
    const int b = bid >> 8, cc = (bid >> 6) & 3, hh = bid & 63;
    const int col = t & 63, r0 = t >> 6;
    #pragma unroll
    for (int i = 0; i < 16; ++i) {
        const int r = i * 4 + r0;
        ls[r][col] = z[((size_t)(b * DIM + cc * 64 + r)) * HW + hh * 64 + col];
    }
    __syncthreads();
    const int pxl = t >> 2, cseg = t & 3;
    const int px = b * HW + hh * 64 + pxl;
    const int sg = cc * 2 + (cseg >> 1);
    union H8 { _Float16 h[8]; int4 v; } ha, hb, la, lb;
    #pragma unroll
    for (int j = 0; j < 16; ++j) {
        const float val = ls[cseg * 16 + j][pxl];
        const _Float16 h = (_Float16)val;
        const _Float16 l = (_Float16)(val - (float)h);
        if (j < 8) { ha.h[j] = h; la.h[j] = l; }
        else       { hb.h[j - 8] = h; lb.h[j - 8] = l; }
    }
    const size_t addr = (size_t)(px >> 7) * 32768 + sg * 4096 + (px & 127) * 32 + (cseg & 1) * 16;
    *reinterpret_cast<int4*>(zh + addr)     = ha.v;
    *reinterpret_cast<int4*>(zh + addr + 8) = hb.v;
    *reinterpret_cast<int4*>(zl + addr)     = la.v;
    *reinterpret_cast<int4*>(zl + addr + 8) = lb.v;
}

// MFMA distance pass: block = 128 pixels x 4096 codes, per-pixel top4
__global__ __launch_bounds__(256, 2) void gemm_kernel(const ushort* __restrict__ eh,
                                                      const ushort* __restrict__ el,
                                                      const ushort* __restrict__ zh,
                                                      const ushort* __restrict__ zl,
                                                      const float* __restrict__ ee,
                                                      const float* __restrict__ zz,
                                                      float* __restrict__ top4v,
                                                      int* __restrict__ top4i) {
    __shared__ __align__(16) char smA_h[8192], smA_l[8192], smB_h[8192], smB_l[8192];
    __shared__ float zz_s[128], ee_s[128];
    __shared__ float mv[2][128][4];
    __shared__ int   mi_[2][128][4];

    const int t = threadIdx.x;
    const int lane = t & 63, w = t >> 6, wr = w >> 1, wc = w & 1;
    const int l15 = lane & 15, l4 = lane >> 4;
    const int px0 = blockIdx.x * 128;

    if (t < 128) zz_s[t] = zz[px0 + t];

    float Tv[4][4]; int Ti[4][4];
    #pragma unroll
    for (int ni = 0; ni < 4; ++ni) {
        #pragma unroll
        for (int j = 0; j < 4; ++j) { Tv[ni][j] = 3.0e38f; Ti[ni][j] = 0; }
    }

    const size_t zbase = (size_t)blockIdx.x * 32768;

    for (int p = 0; p < 32; ++p) {
        f32x4 acc[4][4];
        #pragma unroll
        for (int mi = 0; mi < 4; ++mi)
            #pragma unroll
            for (int ni = 0; ni < 4; ++ni)
                acc[mi][ni] = (f32x4){0.0f, 0.0f, 0.0f, 0.0f};

        for (int s = 0; s < 8; ++s) {
            __syncthreads();
            const size_t ga = (size_t)p * 32768 + s * 4096 + t * 16;
            const size_t gb = zbase + s * 4096 + t * 16;
            const int4 a0 = *reinterpret_cast<const int4*>(eh + ga);
            const int4 a1 = *reinterpret_cast<const int4*>(eh + ga + 8);
            const int4 a2 = *reinterpret_cast<const int4*>(el + ga);
            const int4 a3 = *reinterpret_cast<const int4*>(el + ga + 8);
            const int4 b0 = *reinterpret_cast<const int4*>(zh + gb);
            const int4 b1 = *reinterpret_cast<const int4*>(zh + gb + 8);
            const int4 b2 = *reinterpret_cast<const int4*>(zl + gb);
            const int4 b3 = *reinterpret_cast<const int4*>(zl + gb + 8);
            const int d0 = SWZ(t * 32), d1 = SWZ(t * 32 + 16);
            *reinterpret_cast<int4*>(smA_h + d0) = a0;
            *reinterpret_cast<int4*>(smA_h + d1) = a1;
            *reinterpret_cast<int4*>(smA_l + d0) = a2;
            *reinterpret_cast<int4*>(smA_l + d1) = a3;
            *reinterpret_cast<int4*>(smB_h + d0) = b0;
            *reinterpret_cast<int4*>(smB_h + d1) = b1;
            *reinterpret_cast<int4*>(smB_l + d0) = b2;
            *reinterpret_cast<int4*>(smB_l + d1) = b3;
            if (s == 0 && t < 128) ee_s[t] = ee[p * 128 + t];
            __syncthreads();

            f16x8 bH[4], bL[4];
            #pragma unroll
            for (int ni = 0; ni < 4; ++ni) {
                const int ob = SWZ((wc * 64 + ni * 16 + l15) * 64 + l4 * 16);
                bH[ni] = *reinterpret_cast<const f16x8*>(smB_h + ob);
                bL[ni] = *reinterpret_cast<const f16x8*>(smB_l + ob);
            }
            #pragma unroll
            for (int mi = 0; mi < 4; ++mi) {
                const int oa = SWZ((wr * 64 + mi * 16 + l15) * 64 + l4 * 16);
                const f16x8 aH = *reinterpret_cast<const f16x8*>(smA_h + oa);
                const f16x8 aL = *reinterpret_cast<const f16x8*>(smA_l + oa);
                #pragma unroll
                for (int ni = 0; ni < 4; ++ni) {
                    acc[mi][ni] = __builtin_amdgcn_mfma_f32_16x16x32_f16(aH, bH[ni], acc[mi][ni], 0, 0, 0);
                    acc[mi][ni] = __builtin_amdgcn_mfma_f32_16x16x32_f16(aH, bL[ni], acc[mi][ni], 0, 0, 0);
                    acc[mi][ni] = __builtin_amdgcn_mfma_f32_16x16x32_f16(aL, bH[ni], acc[mi][ni], 0, 0, 0);
                }
            }
        }
        // epilogue: d = fl(t - acc*2^-11), top4 update (ascending k)
        #pragma unroll
        for (int ni = 0; ni < 4; ++ni) {
            const float zzc = zz_s[wc * 64 + ni * 16 + l15];
            #pragma unroll
            for (int mi = 0; mi < 4; ++mi) {
                #pragma unroll
                for (int r = 0; r < 4; ++r) {
                    const int rowb = wr * 64 + mi * 16 + l4 * 4 + r;
                    const float tt = zzc + ee_s[rowb];
                    const float d = fmaf(acc[mi][ni][r], -4.8828125e-4f, tt);
                    const int k = p * 128 + rowb;
                    INS4(Tv[ni], Ti[ni], d, k);
                }
            }
        }
    }

    // cross-lane merge (lanes sharing the same col: l ^ 16, l ^ 32)
    #pragma unroll
    for (int ni = 0; ni < 4; ++ni) {
        #pragma unroll
        for (int m = 16; m <= 32; m <<= 1) {
            float ov[4]; int oi[4];
            #pragma unroll
            for (int j = 0; j < 4; ++j) {
                ov[j] = __shfl_xor(Tv[ni][j], m, 64);
                oi[j] = __shfl_xor(Ti[ni][j], m, 64);
            }
            #pragma unroll
            for (int j = 0; j < 4; ++j) INS4(Tv[ni], Ti[ni], ov[j], oi[j]);
        }
    }
    // cross-wave (wr) merge via LDS
    if (lane < 16) {
        #pragma unroll
        for (int ni = 0; ni < 4; ++ni) {
            const int c = wc * 64 + ni * 16 + lane;
            #pragma unroll
            for (int j = 0; j < 4; ++j) { mv[wr][c][j] = Tv[ni][j]; mi_[wr][c][j] = Ti[ni][j]; }
        }
    }
    __syncthreads();
    if (t < 128) {
        float fv[4]; int fi[4];
        #pragma unroll
        for (int j = 0; j < 4; ++j) { fv[j] = mv[0][t][j]; fi[j] = mi_[0][t][j]; }
        #pragma unroll
        for (int j = 0; j < 4; ++j) INS4(fv, fi, mv[1][t][j], mi_[1][t][j]);
        const int px = px0 + t;
        *reinterpret_cast<float4*>(top4v + (size_t)px * 4) = make_float4(fv[0], fv[1], fv[2], fv[3]);
        *reinterpret_cast<int4*>(top4i + (size_t)px * 4)   = make_int4(fi[0], fi[1], fi[2], fi[3]);
    }
}

// resolve: shortcut / np-exact candidate re-evaluation / rescan flagging
__global__ __launch_bounds__(256) void resolve_kernel(const float* __restrict__ z,
                                                      const float* __restrict__ emb,
                                                      const float* __restrict__ zz,
                                                      const float* __restrict__ ee,
                                                      const float* __restrict__ top4v,
                                                      const int* __restrict__ top4i,
                                                      int* __restrict__ idxf,
                                                      int* __restrict__ cnt,
                                                      int* __restrict__ rlist) {
    const int n = blockIdx.x * 256 + threadIdx.x;
    const float4 vv = *reinterpret_cast<const float4*>(top4v + (size_t)n * 4);
    const int4   ii = *reinterpret_cast<const int4*>(top4i + (size_t)n * 4);
    const float v[4] = {vv.x, vv.y, vv.z, vv.w};
    const int   id[4] = {ii.x, ii.y, ii.z, ii.w};
    const float lim = v[0] + EPSW;
    if (v[1] > lim) { idxf[n] = id[0]; return; }
    if (v[3] <= lim) {                       // can't certify top4 covers window
        idxf[n] = id[0];                     // provisional; rescan overwrites
        const int pos = atomicAdd(cnt, 1);
        rlist[pos] = n;
        return;
    }
    int ck[4]; int nc = 0;
    for (int j = 0; j < 4; ++j) if (v[j] <= lim) ck[nc++] = id[j];
    for (int a = 0; a < nc - 1; ++a)          // sort by k ascending
        for (int b2 = a + 1; b2 < nc; ++b2)
            if (ck[b2] < ck[a]) { int tmp = ck[a]; ck[a] = ck[b2]; ck[b2] = tmp; }
    float best = 0.0f; int bk = -1;
    for (int a = 0; a < nc; ++a) {
        const float d = np_dist(z, emb, zz, ee, n, ck[a]);
        if (bk < 0 || d < best) { best = d; bk = ck[a]; }
    }
    idxf[n] = bk;
}

// full np-exact rescan for flagged pixels (rare)
__global__ __launch_bounds__(256) void rescan_kernel(const float* __restrict__ z,
                                                     const float* __restrict__ emb,
                                                     const float* __restrict__ zz,
                                                     const float* __restrict__ ee,
                                                     const int* __restrict__ cnt,
                                                     const int* __restrict__ rlist,
                                                     int* __restrict__ idxf) {
#pragma clang fp contract(off)
    __shared__ float ls[DIM];
    __shared__ float bv[256];
    __shared__ int   bk[256];
    const int t = threadIdx.x;
    const int count = *cnt;
    for (int e = blockIdx.x; e < count; e += gridDim.x) {
        const int n = rlist[e];
        const int b = n >> 12, hw = n & (HW - 1);
        __syncthreads();
        ls[t] = z[((size_t)(b * DIM + t)) * HW + hw];
        __syncthreads();
        float bestd = 3.0e38f; int besti = -1;
        for (int j = 0; j < 16; ++j) {
            const int k = t + j * 256;
            const float* ep = emb + (size_t)k * DIM;
            float m = 0.0f;
            for (int i = 0; i < DIM; ++i) m = fmaf(ls[i], ep[i], m);
            const float d = (zz[n] + ee[k]) - 2.0f * m;
            if (besti < 0 || d < bestd) { bestd = d; besti = k; }
        }
        bv[t] = bestd; bk[t] = besti;
        __syncthreads();
        if (t == 0) {
            float bd = bv[0]; int bi = bk[0];
            for (int q = 1; q < 256; ++q)
                if (bv[q] < bd || (bv[q] == bd && bk[q] < bi)) { bd = bv[q]; bi = bk[q]; }
            idxf[n] = bi;
        }
    }
}

// gather z_q + idx output + loss partials
__global__ __launch_bounds__(256) void gather_kernel(const float* __restrict__ z,
                                                     const float* __restrict__ emb,
                                                     const int* __restrict__ idxf,
                                                     float* __restrict__ out,
                                                     float* __restrict__ part) {
    __shared__ int   idx_s[32];
    __shared__ float wred[4];
    const int tid = threadIdx.x;
    const int tx = tid & 31, ty = tid >> 5;
    const int m0 = blockIdx.x * 32;
    const int bimg = m0 >> 12, hw0 = m0 & (HW - 1);
    if (tid < 32) {
        const int ii = idxf[m0 + tid];
        idx_s[tid] = ii;
        out[NQ + m0 + tid] = (float)ii;
    }
    __syncthreads();
    float lsum = 0.0f;
    const size_t ebase = (size_t)idx_s[tx] * DIM;
    for (int it = 0; it < DIM / 8; ++it) {
        const int c = it * 8 + ty;
        const float e = emb[ebase + c];
        const size_t zoff = ((size_t)(bimg * DIM + c)) * HW + hw0 + tx;
        out[zoff] = e;
        const float diff = e - z[zoff];
        lsum += diff * diff;
    }
    #pragma unroll
    for (int off = 32; off >= 1; off >>= 1) lsum += __shfl_down(lsum, off, 64);
    if ((tid & 63) == 0) wred[tid >> 6] = lsum;
    __syncthreads();
    if (tid == 0) part[blockIdx.x] = wred[0] + wred[1] + wred[2] + wred[3];
}

__global__ __launch_bounds__(256) void loss_kernel(const float* __restrict__ part,
                                                   int nblk, float* __restrict__ out) {
    __shared__ float wred[4];
    const int tid = threadIdx.x;
    float s = 0.0f;
    for (int i = tid; i < nblk; i += 256) s += part[i];
    #pragma unroll
    for (int off = 32; off >= 1; off >>= 1) s += __shfl_down(s, off, 64);
    if ((tid & 63) == 0) wred[tid >> 6] = s;
    __syncthreads();
    if (tid == 0) {
        const float total = wred[0] + wred[1] + wred[2] + wred[3];
        out[NQ + NPIX] = 1.25f * total / 16777216.0f;
    }
}

// ---------------------------------------------------------------------------
// SAFE path: R3's proven fused VALU kernel (used when ws too small)
// ---------------------------------------------------------------------------
#define MP 32
#define KC 128
#define DC 32
__global__ __launch_bounds__(256) void safe_dist_kernel(const float* __restrict__ z,
                                                        const float* __restrict__ emb,
                                                        const float* __restrict__ ee,
                                                        const float* __restrict__ zz,
                                                        float* __restrict__ out,
                                                        float* __restrict__ part) {
    __shared__ float zs[MP][DIM + 4];
    __shared__ float est[DC][KC + 4];
    __shared__ float ee_s[KC];
    __shared__ float zz_s[MP];
    __shared__ float red_v[MP][33];
    __shared__ int   red_i[MP][33];
    __shared__ int   idx_s[MP];
    __shared__ float wred[4];

    const int tid = threadIdx.x;
    const int tx = tid & 31, ty = tid >> 5;
    const int m0 = blockIdx.x * MP;
    const int bimg = m0 >> 12, hw0 = m0 & (HW - 1);

    for (int c = ty; c < DIM; c += 8)
        zs[tx][c] = z[((size_t)(bimg * DIM + c)) * HW + hw0 + tx];
    if (tid < MP) zz_s[tid] = zz[m0 + tid];

    float minv[4]; int mini[4];
    #pragma unroll
    for (int p = 0; p < 4; ++p) { minv[p] = 3.0e38f; mini[p] = 0; }
    const int rl = tid >> 3, cl = tid & 7;

    for (int kc = 0; kc < KCODES / KC; ++kc) {
        float acc[4][4];
        #pragma unroll
        for (int p = 0; p < 4; ++p)
            #pragma unroll
            for (int q = 0; q < 4; ++q) acc[p][q] = 0.0f;
        for (int dc = 0; dc < DIM / DC; ++dc) {
            __syncthreads();
            if (dc == 0 && tid < KC) ee_s[tid] = ee[kc * KC + tid];
            #pragma unroll
            for (int it = 0; it < 4; ++it) {
                const int kl = it * 32 + rl;
                const float4 v = *reinterpret_cast<const float4*>(
                    emb + (size_t)(kc * KC + kl) * DIM + dc * DC + cl * 4);
                est[cl * 4 + 0][kl] = v.x;
                est[cl * 4 + 1][kl] = v.y;
                est[cl * 4 + 2][kl] = v.z;
                est[cl * 4 + 3][kl] = v.w;
            }
            __syncthreads();
            #pragma unroll
            for (int g = 0; g < DC / 4; ++g) {
                float4 zr[4];
                #pragma unroll
                for (int p = 0; p < 4; ++p)
                    zr[p] = *reinterpret_cast<const float4*>(&zs[ty * 4 + p][dc * DC + g * 4]);
                float4 er[4];
                #pragma unroll
                for (int j = 0; j < 4; ++j)
                    er[j] = *reinterpret_cast<const float4*>(&est[g * 4 + j][tx * 4]);
                #pragma unroll
                for (int p = 0; p < 4; ++p) {
                    acc[p][0] = fmaf(zr[p].x, er[0].x, acc[p][0]);
                    acc[p][0] = fmaf(zr[p].y, er[1].x, acc[p][0]);
                    acc[p][0] = fmaf(zr[p].z, er[2].x, acc[p][0]);
                    acc[p][0] = fmaf(zr[p].w, er[3].x, acc[p][0]);
                    acc[p][1] = fmaf(zr[p].x, er[0].y, acc[p][1]);
                    acc[p][1] = fmaf(zr[p].y, er[1].y, acc[p][1]);
                    acc[p][1] = fmaf(zr[p].z, er[2].y, acc[p][1]);
                    acc[p][1] = fmaf(zr[p].w, er[3].y, acc[p][1]);
                    acc[p][2] = fmaf(zr[p].x, er[0].z, acc[p][2]);
                    acc[p][2] = fmaf(zr[p].y, er[1].z, acc[p][2]);
                    acc[p][2] = fmaf(zr[p].z, er[2].z, acc[p][2]);
                    acc[p][2] = fmaf(zr[p].w, er[3].z, acc[p][2]);
                    acc[p][3] = fmaf(zr[p].x, er[0].w, acc[p][3]);
                    acc[p][3] = fmaf(zr[p].y, er[1].w, acc[p][3]);
                    acc[p][3] = fmaf(zr[p].z, er[2].w, acc[p][3]);
                    acc[p][3] = fmaf(zr[p].w, er[3].w, acc[p][3]);
                }
            }
        }
        #pragma unroll
        for (int q = 0; q < 4; ++q) {
            const int kg = kc * KC + tx * 4 + q;
            const float en = ee_s[tx * 4 + q];
            #pragma unroll
            for (int p = 0; p < 4; ++p) {
                const float t = zz_s[ty * 4 + p] + en;
                const float d = t - 2.0f * acc[p][q];
                if (d < minv[p]) { minv[p] = d; mini[p] = kg; }
            }
        }
    }
    #pragma unroll
    for (int p = 0; p < 4; ++p) {
        red_v[ty * 4 + p][tx] = minv[p];
        red_i[ty * 4 + p][tx] = mini[p];
    }
    __syncthreads();
    if (tid < MP) {
        float bvv = red_v[tid][0]; int bii = red_i[tid][0];
        for (int q = 1; q < 32; ++q) {
            const float vq = red_v[tid][q]; const int iq = red_i[tid][q];
            if (vq < bvv || (vq == bvv && iq < bii)) { bvv = vq; bii = iq; }
        }
        idx_s[tid] = bii;
        out[NQ + m0 + tid] = (float)bii;
    }
    __syncthreads();
    float lsum = 0.0f;
    const size_t ebase = (size_t)idx_s[tx] * DIM;
    for (int it = 0; it < DIM / 8; ++it) {
        const int c = it * 8 + ty;
        const float e = emb[ebase + c];
        out[((size_t)(bimg * DIM + c)) * HW + hw0 + tx] = e;
        const float diff = e - zs[tx][c];
        lsum += diff * diff;
    }
    #pragma unroll
    for (int off = 32; off >= 1; off >>= 1) lsum += __shfl_down(lsum, off, 64);
    if ((tid & 63) == 0) wred[tid >> 6] = lsum;
    __syncthreads();
    if (tid == 0) part[blockIdx.x] = wred[0] + wred[1] + wred[2] + wred[3];
}

// ---------------------------------------------------------------------------
extern "C" void kernel_launch(void* const* d_in, const int* in_sizes, int n_in,
                              void* d_out, int out_size, void* d_ws, size_t ws_size,
                              hipStream_t stream) {
    const float* z   = (const float*)d_in[0];
    const float* emb = (const float*)d_in[1];
    float* out = (float*)d_out;
    char*  ws  = (char*)d_ws;

    // shared small region
    float* zz   = (float*)(ws + 0);            // 256K
    float* ee   = (float*)(ws + 262144);       // 16K
    float* part = (float*)(ws + 278528);       // 8K
    int*   cnt  = (int*)  (ws + 286720);       // 4K
    int*   rlst = (int*)  (ws + 290816);       // 256K
    int*   idxf = (int*)  (ws + 552960);       // 256K
    float* t4v  = (float*)(ws + 1048576);      // 1M
    int*   t4i  = (int*)  (ws + 2097152);      // 1M
    ushort* eh  = (ushort*)(ws + 3145728);     // 2M
    ushort* el  = (ushort*)(ws + 5242880);     // 2M
    ushort* zh  = (ushort*)(ws + 7340032);     // 32M
    ushort* zl  = (ushort*)(ws + 40894464);    // 32M
    const size_t REQ = 74448896;               // ~71 MB

    ee_np_kernel<<<KCODES / 256, 256, 0, stream>>>(emb, ee);
    zz_np_kernel<<<NPIX / 256, 256, 0, stream>>>(z, zz);

    if (ws_size >= REQ) {
        init_kernel<<<1, 64, 0, stream>>>(cnt);
        cvt_emb_kernel<<<KCODES / 4, 256, 0, stream>>>(emb, eh, el);
        cvt_z_kernel<<<4096, 256, 0, stream>>>(z, zh, zl);
        gemm_kernel<<<NPIX / 128, 256, 0, stream>>>(eh, el, zh, zl, ee, zz, t4v, t4i);
        resolve_kernel<<<NPIX / 256, 256, 0, stream>>>(z, emb, zz, ee, t4v, t4i, idxf, cnt, rlst);
        rescan_kernel<<<64, 256, 0, stream>>>(z, emb, zz, ee, cnt, rlst, idxf);
        gather_kernel<<<NPIX / 32, 256, 0, stream>>>(z, emb, idxf, out, part);
        loss_kernel<<<1, 256, 0, stream>>>(part, NPIX / 32, out);
    } else {
        safe_dist_kernel<<<NPIX / MP, 256, 0, stream>>>(z, emb, ee, zz, out, part);
        loss_kernel<<<1, 256, 0, stream>>>(part, NPIX / MP, out);
    }
}